// Round 8
// baseline (501.860 us; speedup 1.0000x reference)
//
#include <hip/hip_runtime.h>

#define DIMM 768
#define NH 12
#define HD 64
#define LSEQ 1024
#define BATCH 4
#define NXE 3145728   // 4096*768
#define NWE 589824    // 768*768

typedef __bf16 bf16x8 __attribute__((ext_vector_type(8)));
typedef float f32x4 __attribute__((ext_vector_type(4)));
typedef unsigned short u16;

static __device__ __forceinline__ u16 f2bf(float f) {
  unsigned u = __builtin_bit_cast(unsigned, f);
  u += 0x7fffu + ((u >> 16) & 1u);
  return (u16)(u >> 16);
}
static __device__ __forceinline__ float bf2f(u16 h) {
  unsigned u = ((unsigned)h) << 16;
  return __builtin_bit_cast(float, u);
}
static __device__ __forceinline__ bf16x8 ld8bf(const u16* p) {
  uint4 u = *(const uint4*)p;
  return __builtin_bit_cast(bf16x8, u);
}
#define MFMA(a, b, c) __builtin_amdgcn_mfma_f32_16x16x32_bf16(a, b, c, 0, 0, 0)
#define GLL(g, s)                                                      \
  __builtin_amdgcn_global_load_lds(                                    \
      (const __attribute__((address_space(1))) void*)(g),              \
      (__attribute__((address_space(3))) void*)(s), 16, 0, 0)

// ---------- Kernel 0: fp32 -> bf16 hi/lo conversion prepass ----------
__global__ __launch_bounds__(256) void convert(
    const float* __restrict__ q_in, const float* __restrict__ k_in,
    const float* __restrict__ v_in, const float* __restrict__ Wq,
    const float* __restrict__ Wk, const float* __restrict__ Wv,
    const float* __restrict__ Wp, u16* __restrict__ AqH, u16* __restrict__ AqL,
    u16* __restrict__ AkH, u16* __restrict__ AkL, u16* __restrict__ Av,
    u16* __restrict__ WqH, u16* __restrict__ WqL, u16* __restrict__ WkH,
    u16* __restrict__ WkL, u16* __restrict__ Wvr, u16* __restrict__ Wpr) {
  long i = ((long)blockIdx.x * 256 + threadIdx.x) * 4;
  const float* src;
  u16 *dh, *dl = nullptr;
  long off;
  if (i < NXE) { src = q_in; dh = AqH; dl = AqL; off = i; }
  else if (i < 2L * NXE) { src = k_in; dh = AkH; dl = AkL; off = i - NXE; }
  else if (i < 3L * NXE) { src = v_in; dh = Av; off = i - 2L * NXE; }
  else {
    long j = i - 3L * NXE;
    int which = (int)(j / NWE);
    off = j % NWE;
    if (which == 0) { src = Wq; dh = WqH; dl = WqL; }
    else if (which == 1) { src = Wk; dh = WkH; dl = WkL; }
    else if (which == 2) { src = Wv; dh = Wvr; }
    else { src = Wp; dh = Wpr; }
  }
  float4 v = *(const float4*)(src + off);
  ushort4 h;
  h.x = f2bf(v.x); h.y = f2bf(v.y); h.z = f2bf(v.z); h.w = f2bf(v.w);
  *(ushort4*)(dh + off) = h;
  if (dl) {
    ushort4 lo;
    lo.x = f2bf(v.x - bf2f(h.x)); lo.y = f2bf(v.y - bf2f(h.y));
    lo.z = f2bf(v.z - bf2f(h.z)); lo.w = f2bf(v.w - bf2f(h.w));
    *(ushort4*)(dl + off) = lo;
  }
}

// ---------- Kernel 1/3: 128x128-tile LDS-staged MFMA GEMM ----------
__global__ __launch_bounds__(256, 3) void gemm_multi(
    int mode0, const u16* __restrict__ AqH, const u16* __restrict__ AqL,
    const u16* __restrict__ AkH, const u16* __restrict__ AkL,
    const u16* __restrict__ Av, const u16* __restrict__ WqH,
    const u16* __restrict__ WqL, const u16* __restrict__ WkH,
    const u16* __restrict__ WkL, const u16* __restrict__ Wvr,
    const u16* __restrict__ Wpr, const u16* __restrict__ wbuf,
    u16* __restrict__ qhi, u16* __restrict__ qlo, u16* __restrict__ khi,
    u16* __restrict__ klo, u16* __restrict__ vT, float* __restrict__ outp,
    const float* __restrict__ bias) {
  __shared__ u16 sAh[128 * 32], sAl[128 * 32];
  __shared__ u16 sBh[128 * 32], sBl[128 * 32];
  const int mode = mode0 + blockIdx.z;
  const u16 *Ah, *Al = nullptr, *Bh, *Bl = nullptr;
  if (mode == 0) { Ah = AqH; Al = AqL; Bh = WqH; Bl = WqL; }
  else if (mode == 1) { Ah = AkH; Al = AkL; Bh = WkH; Bl = WkL; }
  else if (mode == 2) { Ah = Av; Bh = Wvr; }
  else { Ah = wbuf; Bh = Wpr; }
  const int t = threadIdx.x, w = t >> 6, l = t & 63;
  const int quad = l >> 4, l15 = l & 15;
  const int m0 = blockIdx.x * 128, n0 = blockIdx.y * 128;
  const int wm = (w >> 1) * 64, wn = (w & 1) * 64;
  const int srow = t >> 2, scol = (t & 3) * 8;
  const u16* gA = Ah + (m0 + srow) * DIMM + scol;
  const u16* gB = Bh + (n0 + srow) * DIMM + scol;
  u16* lA = sAh + w * 512;
  u16* lB = sBh + w * 512;
  f32x4 acc[4][4] = {};
  if (mode < 2) {
    const u16* gAl = Al + (m0 + srow) * DIMM + scol;
    const u16* gBl = Bl + (n0 + srow) * DIMM + scol;
    u16* lAl = sAl + w * 512;
    u16* lBl = sBl + w * 512;
    for (int k0 = 0; k0 < DIMM; k0 += 32) {
      GLL(gA + k0, lA);
      GLL(gA + 64 * DIMM + k0, lA + 2048);
      GLL(gAl + k0, lAl);
      GLL(gAl + 64 * DIMM + k0, lAl + 2048);
      GLL(gB + k0, lB);
      GLL(gB + 64 * DIMM + k0, lB + 2048);
      GLL(gBl + k0, lBl);
      GLL(gBl + 64 * DIMM + k0, lBl + 2048);
      __syncthreads();
      bf16x8 ah[4], bh[4], xl[4];
#pragma unroll
      for (int i = 0; i < 4; ++i)
        ah[i] = __builtin_bit_cast(
            bf16x8, *(const uint4*)(sAh + (wm + i * 16 + l15) * 32 + quad * 8));
#pragma unroll
      for (int j = 0; j < 4; ++j)
        bh[j] = __builtin_bit_cast(
            bf16x8, *(const uint4*)(sBh + (wn + j * 16 + l15) * 32 + quad * 8));
#pragma unroll
      for (int i = 0; i < 4; ++i)
#pragma unroll
        for (int j = 0; j < 4; ++j) acc[i][j] = MFMA(ah[i], bh[j], acc[i][j]);
#pragma unroll
      for (int i = 0; i < 4; ++i)
        xl[i] = __builtin_bit_cast(
            bf16x8, *(const uint4*)(sAl + (wm + i * 16 + l15) * 32 + quad * 8));
#pragma unroll
      for (int i = 0; i < 4; ++i)
#pragma unroll
        for (int j = 0; j < 4; ++j) acc[i][j] = MFMA(xl[i], bh[j], acc[i][j]);
#pragma unroll
      for (int j = 0; j < 4; ++j)
        xl[j] = __builtin_bit_cast(
            bf16x8, *(const uint4*)(sBl + (wn + j * 16 + l15) * 32 + quad * 8));
#pragma unroll
      for (int i = 0; i < 4; ++i)
#pragma unroll
        for (int j = 0; j < 4; ++j) acc[i][j] = MFMA(ah[i], xl[j], acc[i][j]);
      __syncthreads();
    }
  } else {
    for (int k0 = 0; k0 < DIMM; k0 += 32) {
      GLL(gA + k0, lA);
      GLL(gA + 64 * DIMM + k0, lA + 2048);
      GLL(gB + k0, lB);
      GLL(gB + 64 * DIMM + k0, lB + 2048);
      __syncthreads();
      bf16x8 ah[4], bh[4];
#pragma unroll
      for (int i = 0; i < 4; ++i)
        ah[i] = __builtin_bit_cast(
            bf16x8, *(const uint4*)(sAh + (wm + i * 16 + l15) * 32 + quad * 8));
#pragma unroll
      for (int j = 0; j < 4; ++j)
        bh[j] = __builtin_bit_cast(
            bf16x8, *(const uint4*)(sBh + (wn + j * 16 + l15) * 32 + quad * 8));
#pragma unroll
      for (int i = 0; i < 4; ++i)
#pragma unroll
        for (int j = 0; j < 4; ++j) acc[i][j] = MFMA(ah[i], bh[j], acc[i][j]);
      __syncthreads();
    }
  }
  u16* oh = (mode == 0) ? qhi : khi;
  u16* ol = (mode == 0) ? qlo : klo;
#pragma unroll
  for (int i = 0; i < 4; ++i)
#pragma unroll
    for (int j = 0; j < 4; ++j)
#pragma unroll
      for (int r = 0; r < 4; ++r) {
        int grow = m0 + wm + i * 16 + quad * 4 + r;  // (b,l)
        int gcol = n0 + wn + j * 16 + l15;           // (h,d)
        float c = acc[i][j][r];
        int b = grow >> 10, ll = grow & 1023, h = gcol >> 6, d = gcol & 63;
        if (mode < 2) {
          int idx = ((b * NH + h) * LSEQ + ll) * HD + d;
          u16 hi = f2bf(c);
          oh[idx] = hi;
          ol[idx] = f2bf(c - bf2f(hi));
        } else if (mode == 2) {
          vT[((b * NH + h) * HD + d) * LSEQ + ll] = f2bf(c);
        } else {
          outp[grow * DIMM + gcol] = c + bias[gcol];
        }
      }
}

// ---------- Kernel 2: attention core, 32 q-rows/block, K dbuf ----------
__global__ __launch_bounds__(256, 2) void attn_core(
    const u16* __restrict__ qhi, const u16* __restrict__ qlo,
    const u16* __restrict__ khi, const u16* __restrict__ klo,
    const u16* __restrict__ vT, const float* __restrict__ relk,
    const float* __restrict__ relv, float* __restrict__ attn_out,
    u16* __restrict__ wbuf) {
  // union: phase1 = 2 x 16KB K-stage dbuf; phase2+ = Pb[32][1032] bf16 (66 KB)
  __shared__ __align__(16) u16 uni[32 * 1032];
  __shared__ float qrel[32][7];
  __shared__ float arel[32][7];
  __shared__ float rvt[7][64];
  __shared__ float red[4][32][4];

  const int qt = blockIdx.x, h = blockIdx.y, b = blockIdx.z;
  const int q0 = qt * 32;
  const int tid = threadIdx.x, wave = tid >> 6, lane = tid & 63;
  const int quad = lane >> 4, l15 = lane & 15;
  const int bhd = b * NH + h;

  // phase 0: rel_v -> LDS; qrel[32][7]; zero arel
  for (int t = tid; t < 7 * HD; t += 256) rvt[t >> 6][t & 63] = relv[t];
  if (tid < 224) {
    int q = tid / 7, rr = tid % 7;
    const u16* qp = qhi + (bhd * LSEQ + q0 + q) * HD;
    const u16* lp = qlo + (bhd * LSEQ + q0 + q) * HD;
    const float* tp = relk + rr * HD;
    float s = 0.f;
#pragma unroll
    for (int d8 = 0; d8 < HD; d8 += 8) {
      uint4 uh = *(const uint4*)(qp + d8);
      uint4 ul = *(const uint4*)(lp + d8);
      float4 t0 = *(const float4*)(tp + d8);
      float4 t1 = *(const float4*)(tp + d8 + 4);
      unsigned hh[4] = {uh.x, uh.y, uh.z, uh.w};
      unsigned lv[4] = {ul.x, ul.y, ul.z, ul.w};
      float tv[8] = {t0.x, t0.y, t0.z, t0.w, t1.x, t1.y, t1.z, t1.w};
#pragma unroll
      for (int m = 0; m < 4; ++m) {
        s += (bf2f((u16)(hh[m] & 0xffff)) + bf2f((u16)(lv[m] & 0xffff))) * tv[2 * m];
        s += (bf2f((u16)(hh[m] >> 16)) + bf2f((u16)(lv[m] >> 16))) * tv[2 * m + 1];
      }
    }
    qrel[q][rr] = s;
    arel[q][rr] = 0.f;
  }

  // phase 1: S = Q K^T (hi/lo 3-term), 2 q-tiles, K dbuf via GLL
  f32x4 sc[2][16];
  {
    bf16x8 ah[2][2], al[2][2];
#pragma unroll
    for (int qq = 0; qq < 2; ++qq) {
      const int qbase = (bhd * LSEQ + q0 + qq * 16 + l15) * HD + quad * 8;
      ah[qq][0] = ld8bf(qhi + qbase);
      ah[qq][1] = ld8bf(qhi + qbase + 32);
      al[qq][0] = ld8bf(qlo + qbase);
      al[qq][1] = ld8bf(qlo + qbase + 32);
    }
    const int r = tid >> 3;              // staged K row 0..31
    const int cg = (tid & 7) ^ (r & 7);  // XOR swizzle
    const u16* gh = khi + (bhd * LSEQ + r) * HD + cg * 8;
    const u16* gl = klo + (bhd * LSEQ + r) * HD + cg * 8;
    const int rowA = wave * 16 + l15;
    const int sw = rowA & 7;
    const int s0 = (rowA * 8 + (quad ^ sw)) * 8;
    const int s1 = (rowA * 8 + ((quad + 4) ^ sw)) * 8;
    {  // prologue: chunk 0 -> buf 0
      u16* sb = uni + wave * 512;
      GLL(gh, sb);
      GLL(gh + 32 * HD, sb + 2048);
      GLL(gl, sb + 4096);
      GLL(gl + 32 * HD, sb + 6144);
    }
    for (int c = 0; c < 16; ++c) {
      __syncthreads();  // buf[c&1] ready (drains GLL)
      const int cur = (c & 1) * 8192;
      if (c < 15) {
        u16* sb = uni + ((c + 1) & 1) * 8192 + wave * 512;
        const u16* ghc = gh + (c + 1) * 64 * HD;
        const u16* glc = gl + (c + 1) * 64 * HD;
        GLL(ghc, sb);
        GLL(ghc + 32 * HD, sb + 2048);
        GLL(glc, sb + 4096);
        GLL(glc + 32 * HD, sb + 6144);
      }
      bf16x8 kh0 = ld8bf(uni + cur + s0);
      bf16x8 kh1 = ld8bf(uni + cur + s1);
      bf16x8 kl0 = ld8bf(uni + cur + 4096 + s0);
      bf16x8 kl1 = ld8bf(uni + cur + 4096 + s1);
#pragma unroll
      for (int qq = 0; qq < 2; ++qq) {
        f32x4 e = {}, f = {};
        e = MFMA(ah[qq][0], kh0, e);
        f = MFMA(ah[qq][1], kh1, f);
        e = MFMA(ah[qq][0], kl0, e);
        f = MFMA(ah[qq][1], kl1, f);
        e = MFMA(al[qq][0], kh0, e);
        f = MFMA(al[qq][1], kh1, f);
        sc[qq][c] = e + f;
      }
    }
  }

  // phase 1.5: + rel scores, *8; per-row max
  const int colbase = wave * 16 + l15;  // col = colbase + c*64
  float mrow[2][4] = {{-3.4e38f, -3.4e38f, -3.4e38f, -3.4e38f},
                      {-3.4e38f, -3.4e38f, -3.4e38f, -3.4e38f}};
#pragma unroll
  for (int c = 0; c < 16; ++c)
#pragma unroll
    for (int qq = 0; qq < 2; ++qq)
#pragma unroll
      for (int r = 0; r < 4; ++r) {
        int row = qq * 16 + quad * 4 + r;
        int d = colbase + c * 64 - q0 - row;
        int ri = d < -3 ? 0 : (d > 3 ? 6 : d + 3);
        float s = (sc[qq][c][r] + qrel[row][ri]) * 8.0f;
        sc[qq][c][r] = s;
        mrow[qq][r] = fmaxf(mrow[qq][r], s);
      }
#pragma unroll
  for (int m = 1; m <= 8; m <<= 1)
#pragma unroll
    for (int qq = 0; qq < 2; ++qq)
#pragma unroll
      for (int r = 0; r < 4; ++r)
        mrow[qq][r] = fmaxf(mrow[qq][r], __shfl_xor(mrow[qq][r], m));
  if (l15 < 4) {
#pragma unroll
    for (int qq = 0; qq < 2; ++qq) {
      float mv = l15 == 0 ? mrow[qq][0] : l15 == 1 ? mrow[qq][1]
                 : l15 == 2 ? mrow[qq][2] : mrow[qq][3];
      red[0][qq * 16 + quad * 4 + l15][wave] = mv;
    }
  }
  __syncthreads();
  float mx[2][4];
#pragma unroll
  for (int qq = 0; qq < 2; ++qq)
#pragma unroll
    for (int r = 0; r < 4; ++r) {
      int row = qq * 16 + quad * 4 + r;
      mx[qq][r] = fmaxf(fmaxf(red[0][row][0], red[0][row][1]),
                        fmaxf(red[0][row][2], red[0][row][3]));
    }

  // phase 2: exp + partial sums (total, d<=-3, d>=3)
  float sum[2][4] = {}, s0a[2][4] = {}, s6a[2][4] = {};
#pragma unroll
  for (int c = 0; c < 16; ++c)
#pragma unroll
    for (int qq = 0; qq < 2; ++qq)
#pragma unroll
      for (int r = 0; r < 4; ++r) {
        int row = qq * 16 + quad * 4 + r;
        float e = __expf(sc[qq][c][r] - mx[qq][r]);
        sc[qq][c][r] = e;
        int d = colbase + c * 64 - q0 - row;
        sum[qq][r] += e;
        if (d <= -3) s0a[qq][r] += e;
        if (d >= 3) s6a[qq][r] += e;
      }
#pragma unroll
  for (int m = 1; m <= 8; m <<= 1)
#pragma unroll
    for (int qq = 0; qq < 2; ++qq)
#pragma unroll
      for (int r = 0; r < 4; ++r) {
        sum[qq][r] += __shfl_xor(sum[qq][r], m);
        s0a[qq][r] += __shfl_xor(s0a[qq][r], m);
        s6a[qq][r] += __shfl_xor(s6a[qq][r], m);
      }
  if (l15 < 4) {
#pragma unroll
    for (int qq = 0; qq < 2; ++qq) {
      int row = qq * 16 + quad * 4 + l15;
      float sv = l15 == 0 ? sum[qq][0] : l15 == 1 ? sum[qq][1]
                 : l15 == 2 ? sum[qq][2] : sum[qq][3];
      float a0 = l15 == 0 ? s0a[qq][0] : l15 == 1 ? s0a[qq][1]
                 : l15 == 2 ? s0a[qq][2] : s0a[qq][3];
      float a6 = l15 == 0 ? s6a[qq][0] : l15 == 1 ? s6a[qq][1]
                 : l15 == 2 ? s6a[qq][2] : s6a[qq][3];
      red[1][row][wave] = sv;
      red[2][row][wave] = a0;
      red[3][row][wave] = a6;
    }
  }
  __syncthreads();
  float rn[2][4];
#pragma unroll
  for (int qq = 0; qq < 2; ++qq)
#pragma unroll
    for (int r = 0; r < 4; ++r) {
      int row = qq * 16 + quad * 4 + r;
      float s = red[1][row][0] + red[1][row][1] + red[1][row][2] + red[1][row][3];
      rn[qq][r] = 1.0f / s;
      if (wave == 0 && l15 == 0) {
        float t0 = red[2][row][0] + red[2][row][1] + red[2][row][2] + red[2][row][3];
        float t6 = red[3][row][0] + red[3][row][1] + red[3][row][2] + red[3][row][3];
        arel[row][0] = t0 * rn[qq][r];
        arel[row][6] = t6 * rn[qq][r];
      }
    }

  // phase 2c: normalize -> Pb (bf16, LDS) + singleton buckets
#pragma unroll
  for (int c = 0; c < 16; ++c) {
    int col = colbase + c * 64;
#pragma unroll
    for (int qq = 0; qq < 2; ++qq)
#pragma unroll
      for (int r = 0; r < 4; ++r) {
        int row = qq * 16 + quad * 4 + r;
        float p = sc[qq][c][r] * rn[qq][r];
        uni[row * 1032 + col] = f2bf(p);
        int d = col - q0 - row;
        if (d >= -2 && d <= 2) arel[row][d + 3] = p;
      }
  }
  __syncthreads();

  // phase 2d: coalesced fp32 attn store from Pb
  {
    float* aob = attn_out + ((size_t)(bhd * LSEQ + q0)) * LSEQ;
#pragma unroll
    for (int row = 0; row < 32; ++row) {
      uint2 u = *(const uint2*)&uni[row * 1032 + tid * 4];
      float4 f = {bf2f((u16)(u.x & 0xffff)), bf2f((u16)(u.x >> 16)),
                  bf2f((u16)(u.y & 0xffff)), bf2f((u16)(u.y >> 16))};
      *(float4*)(aob + row * LSEQ + tid * 4) = f;
    }
  }

  // phase 3: W1 = P @ V (wave -> 16 d-cols, 2 q-tiles) + W2 = arel @ rel_v
  {
    const u16* vb = vT + (bhd * HD + wave * 16 + l15) * LSEQ;
    f32x4 acc[2] = {};
#pragma unroll 4
    for (int kk = 0; kk < LSEQ; kk += 32) {
      int ak = kk + quad * 8;
      bf16x8 bV = ld8bf(vb + ak);
      bf16x8 aP0 = __builtin_bit_cast(bf16x8, *(const uint4*)&uni[l15 * 1032 + ak]);
      bf16x8 aP1 =
          __builtin_bit_cast(bf16x8, *(const uint4*)&uni[(16 + l15) * 1032 + ak]);
      acc[0] = MFMA(aP0, bV, acc[0]);
      acc[1] = MFMA(aP1, bV, acc[1]);
    }
    const int col = wave * 16 + l15;  // d
#pragma unroll
    for (int qq = 0; qq < 2; ++qq)
#pragma unroll
      for (int r = 0; r < 4; ++r) {
        int row = qq * 16 + quad * 4 + r;
        float w2 = 0.f;
#pragma unroll
        for (int t = 0; t < 7; ++t) w2 += arel[row][t] * rvt[t][col];
        wbuf[(b * LSEQ + q0 + row) * DIMM + h * HD + col] = f2bf(acc[qq][r] + w2);
      }
  }
}

extern "C" void kernel_launch(void* const* d_in, const int* in_sizes, int n_in,
                              void* d_out, int out_size, void* d_ws, size_t ws_size,
                              hipStream_t stream) {
  const float* q_in = (const float*)d_in[0];
  const float* k_in = (const float*)d_in[1];
  const float* v_in = (const float*)d_in[2];
  const float* Wq = (const float*)d_in[3];
  const float* Wk = (const float*)d_in[4];
  const float* Wv = (const float*)d_in[5];
  const float* Wp = (const float*)d_in[6];
  const float* bias = (const float*)d_in[7];
  const float* relk = (const float*)d_in[8];
  const float* relv = (const float*)d_in[9];
  float* out = (float*)d_out;

  u16* p = (u16*)d_ws;
  u16 *AqH = p, *AqL = AqH + NXE, *AkH = AqL + NXE, *AkL = AkH + NXE,
      *Av = AkL + NXE;
  u16 *WqH = Av + NXE, *WqL = WqH + NWE, *WkH = WqL + NWE, *WkL = WkH + NWE,
      *Wvr = WkL + NWE, *Wpr = Wvr + NWE;
  u16 *qhi = Wpr + NWE, *qlo = qhi + NXE, *khi = qlo + NXE, *klo = khi + NXE,
      *vT = klo + NXE, *wbuf = vT + NXE;

  convert<<<(3 * NXE + 4 * NWE) / 1024, 256, 0, stream>>>(
      q_in, k_in, v_in, Wq, Wk, Wv, Wp, AqH, AqL, AkH, AkL, Av, WqH, WqL, WkH,
      WkL, Wvr, Wpr);
  gemm_multi<<<dim3(32, 6, 3), 256, 0, stream>>>(
      0, AqH, AqL, AkH, AkL, Av, WqH, WqL, WkH, WkL, Wvr, Wpr, wbuf, qhi, qlo,
      khi, klo, vT, out, bias);
  attn_core<<<dim3(32, NH, BATCH), 256, 0, stream>>>(
      qhi, qlo, khi, klo, vT, relk, relv, out + NXE, wbuf);
  gemm_multi<<<dim3(32, 6, 1), 256, 0, stream>>>(
      3, AqH, AqL, AkH, AkL, Av, WqH, WqL, WkH, WkL, Wvr, Wpr, wbuf, qhi, qlo,
      khi, klo, vT, out, bias);
}